// Round 3
// baseline (8449.632 us; speedup 1.0000x reference)
//
#include <hip/hip_runtime.h>
#include <hip/hip_bf16.h>
#include <cstddef>

// ---------------------------------------------------------------------------
// LSTM_intensity: T=512 step scan, B=256, H=512, I=256, fused head.
// Strategy: fp16 MFMA 16x16x32, K = 256(x) + 512(h) = 768 folded per step.
// 512 per-step kernel launches (graph-captured). State c fp32, h fp16 pingpong.
// ---------------------------------------------------------------------------

#define T_STEPS 512
#define BATCH 256
#define ISZ 256
#define HID 512
#define KTOT 768          // 256 (x) + 512 (h)
#define KT_STEPS 24       // 768 / 32
#define AP 776            // A-tile LDS row stride in halfs (768 + 8 pad)

typedef _Float16 half8 __attribute__((ext_vector_type(8)));
typedef float f32x4 __attribute__((ext_vector_type(4)));

// ---- workspace layout (bytes) ----
#define WS_XH    0            // 512*256*256 halfs = 67,108,864 B
#define WS_WP    67108864     // 768*2048 halfs    =  3,145,728 B
#define WS_BSUM  70254592     // 2048 f32          =      8,192 B
#define WS_HB0   70262784     // 131072 halfs      =    262,144 B
#define WS_HB1   70524928     // 131072 halfs      =    262,144 B
#define WS_C     70787072     // 131072 f32        =    524,288 B
// total ~71.3 MB

// Convert X fp32 -> fp16 (same [T][B][I] row-major layout)
__global__ void k_convX(const float* __restrict__ X, _Float16* __restrict__ Xh) {
    const size_t n4 = (size_t)T_STEPS * BATCH * ISZ / 4;
    for (size_t i = (size_t)blockIdx.x * blockDim.x + threadIdx.x; i < n4;
         i += (size_t)gridDim.x * blockDim.x) {
        float4 v = ((const float4*)X)[i];
        _Float16 h4[4] = {(_Float16)v.x, (_Float16)v.y, (_Float16)v.z, (_Float16)v.w};
        *(uint2*)(Xh + i * 4) = *(const uint2*)h4;
    }
}

// Pack [W_ih | W_hh] into MFMA-B-fragment-linear fp16 layout.
// Element at tile*512 + lane*8 + i  <->  B[k][n],
//   k = kt*32 + (lane>>4)*8 + i, n = nt*16 + (lane&15), tile = nt*24 + kt.
__global__ void k_pack(const float* __restrict__ Wih, const float* __restrict__ Whh,
                       _Float16* __restrict__ Wp) {
    int idx = blockIdx.x * 256 + threadIdx.x;
    if (idx >= KTOT * 2048) return;
    int i    = idx & 7;
    int lane = (idx >> 3) & 63;
    int tile = idx >> 9;
    int kt = tile % KT_STEPS;
    int nt = tile / KT_STEPS;
    int n = nt * 16 + (lane & 15);
    int k = kt * 32 + (lane >> 4) * 8 + i;
    float v = (k < ISZ) ? Wih[n * ISZ + k] : Whh[n * HID + (k - ISZ)];
    Wp[idx] = (_Float16)v;
}

// bias sum + h0 fp16 convert + c0 copy
__global__ void k_misc(const float* __restrict__ bih, const float* __restrict__ bhh,
                       float* __restrict__ bsum, const float* __restrict__ h0,
                       _Float16* __restrict__ hb, const float* __restrict__ c0,
                       float* __restrict__ cst) {
    int idx = blockIdx.x * 256 + threadIdx.x;   // 131072 threads
    if (idx < 4 * HID) bsum[idx] = bih[idx] + bhh[idx];
    hb[idx] = (_Float16)h0[idx];
    cst[idx] = c0[idx];
}

__device__ __forceinline__ float sigm(float x) { return 1.f / (1.f + __expf(-x)); }
__device__ __forceinline__ float tanh_fast(float x) { return 2.f / (1.f + __expf(-2.f * x)) - 1.f; }

// One LSTM timestep. 128 blocks: bt = blk>>4 (8 b-tiles of 32 rows),
// jt = blk&15 (16 j-tiles of 32 hidden units). 256 threads = 4 waves.
__global__ __launch_bounds__(256) void k_step(
    const _Float16* __restrict__ Xh, const _Float16* __restrict__ Wp,
    const float* __restrict__ bsum,
    const _Float16* __restrict__ hprev, _Float16* __restrict__ hnext,
    float* __restrict__ cst,
    const float* __restrict__ W1, const float* __restrict__ b1,
    const float* __restrict__ W2, const float* __restrict__ b2,
    float* __restrict__ out, int t)
{
    __shared__ _Float16 A[32 * AP];       // [32 rows][768 K + pad]
    __shared__ float yp[32 * 8 * 5];

    const int tid = threadIdx.x;
    const int blk = blockIdx.x;
    const int bt = blk >> 4, jt = blk & 15;
    const int b0 = bt * 32, j0 = jt * 32;

    // ---- stage A-tile: x_t rows (k 0..255) then h_prev rows (k 256..767) ----
    // 3072 16B-chunks total, 12 per thread
    #pragma unroll
    for (int it = 0; it < 12; ++it) {
        int cid = tid + it * 256;
        if (cid < 1024) {
            int r = cid >> 5, kh = (cid & 31) * 8;
            uint4 v = *(const uint4*)(Xh + ((size_t)t * BATCH + b0 + r) * ISZ + kh);
            *(uint4*)&A[r * AP + kh] = v;
        } else {
            int c2 = cid - 1024;
            int r = c2 >> 6, kh = (c2 & 63) * 8;
            uint4 v = *(const uint4*)(hprev + (size_t)(b0 + r) * HID + kh);
            *(uint4*)&A[r * AP + ISZ + kh] = v;
        }
    }
    __syncthreads();

    // ---- dense head for PREVIOUS timestep (h_{t-1} is staged): jt==0 blocks ----
    if (jt == 0 && t > 0) {
        int row = tid >> 3, seg = tid & 7;
        float p[5] = {0.f, 0.f, 0.f, 0.f, 0.f};
        int kbase = seg * 64;
        for (int k = kbase; k < kbase + 64; ++k) {
            float hv = (float)A[row * AP + ISZ + k];
            #pragma unroll
            for (int m = 0; m < 5; ++m) p[m] += hv * W1[m * HID + k];
        }
        #pragma unroll
        for (int m = 0; m < 5; ++m) yp[(row * 8 + seg) * 5 + m] = p[m];
    }
    __syncthreads();
    if (jt == 0 && t > 0 && tid < 32) {
        float z = b2[0];
        #pragma unroll
        for (int m = 0; m < 5; ++m) {
            float am = b1[m];
            for (int s = 0; s < 8; ++s) am += yp[(tid * 8 + s) * 5 + m];
            z += am * W2[m];
        }
        out[(size_t)(t - 1) * BATCH + b0 + tid] = z > 0.f ? z : (__expf(z) - 1.f);
    }

    // ---- MFMA: gates[b0+mh*16..+15][jw..jw+15] for 4 gates, K=768 ----
    const int wave = tid >> 6, lane = tid & 63;
    const int jw = j0 + (wave & 1) * 16;   // 16-col slice
    const int mh = wave >> 1;              // 16-row half of the 32-row tile
    const int ar = mh * 16 + (lane & 15);  // A row in LDS tile
    const int kg = (lane >> 4) * 8;        // k sub-offset within 32-k step

    f32x4 acc[4];
    #pragma unroll
    for (int g = 0; g < 4; ++g) acc[g] = (f32x4){0.f, 0.f, 0.f, 0.f};

    int ntg[4];
    #pragma unroll
    for (int g = 0; g < 4; ++g) ntg[g] = g * 32 + (jw >> 4);

    for (int kt = 0; kt < KT_STEPS; ++kt) {
        half8 a = *(const half8*)&A[ar * AP + kt * 32 + kg];
        #pragma unroll
        for (int g = 0; g < 4; ++g) {
            half8 b = *(const half8*)(Wp + ((size_t)(ntg[g] * KT_STEPS + kt) << 9) + lane * 8);
            acc[g] = __builtin_amdgcn_mfma_f32_16x16x32_f16(a, b, acc[g], 0, 0, 0);
        }
    }

    // ---- epilogue: nonlinearities, c/h update ----
    const int col = lane & 15;
    const int j = jw + col;
    const int rbase = b0 + mh * 16 + ((lane >> 4) << 2);
    const float bi = bsum[j], bf = bsum[HID + j], bg = bsum[2 * HID + j], bo = bsum[3 * HID + j];
    #pragma unroll
    for (int i2 = 0; i2 < 4; ++i2) {
        int r = rbase + i2;
        float gi = acc[0][i2] + bi;
        float gf = acc[1][i2] + bf;
        float gg = acc[2][i2] + bg;
        float go = acc[3][i2] + bo;
        float si = sigm(gi), sf = sigm(gf), tg = tanh_fast(gg), so = sigm(go);
        size_t ci = (size_t)r * HID + j;
        float cn = sf * cst[ci] + si * tg;
        cst[ci] = cn;
        hnext[ci] = (_Float16)(so * tanh_fast(cn));
    }
}

// final head: y_511 from h_511 (in hb0). 8 blocks x 256 threads.
__global__ __launch_bounds__(256) void k_ytail(
    const _Float16* __restrict__ h, const float* __restrict__ W1,
    const float* __restrict__ b1, const float* __restrict__ W2,
    const float* __restrict__ b2, float* __restrict__ out)
{
    __shared__ float yp[32 * 8 * 5];
    const int tid = threadIdx.x;
    const int b0 = blockIdx.x * 32;
    int row = tid >> 3, seg = tid & 7;
    float p[5] = {0.f, 0.f, 0.f, 0.f, 0.f};
    int kbase = seg * 64;
    for (int k = kbase; k < kbase + 64; ++k) {
        float hv = (float)h[(size_t)(b0 + row) * HID + k];
        #pragma unroll
        for (int m = 0; m < 5; ++m) p[m] += hv * W1[m * HID + k];
    }
    #pragma unroll
    for (int m = 0; m < 5; ++m) yp[(row * 8 + seg) * 5 + m] = p[m];
    __syncthreads();
    if (tid < 32) {
        float z = b2[0];
        #pragma unroll
        for (int m = 0; m < 5; ++m) {
            float am = b1[m];
            for (int s = 0; s < 8; ++s) am += yp[(tid * 8 + s) * 5 + m];
            z += am * W2[m];
        }
        out[(size_t)(T_STEPS - 1) * BATCH + b0 + tid] = z > 0.f ? z : (__expf(z) - 1.f);
    }
}

extern "C" void kernel_launch(void* const* d_in, const int* in_sizes, int n_in,
                              void* d_out, int out_size, void* d_ws, size_t ws_size,
                              hipStream_t stream) {
    const float* X   = (const float*)d_in[0];
    const float* h0  = (const float*)d_in[1];
    const float* c0  = (const float*)d_in[2];
    const float* Wih = (const float*)d_in[3];
    const float* Whh = (const float*)d_in[4];
    const float* bih = (const float*)d_in[5];
    const float* bhh = (const float*)d_in[6];
    const float* W1  = (const float*)d_in[7];
    const float* b1  = (const float*)d_in[8];
    const float* W2  = (const float*)d_in[9];
    const float* b2  = (const float*)d_in[10];
    float* out = (float*)d_out;

    char* ws = (char*)d_ws;
    _Float16* Xh   = (_Float16*)(ws + WS_XH);
    _Float16* Wp   = (_Float16*)(ws + WS_WP);
    float*    bsum = (float*)(ws + WS_BSUM);
    _Float16* hb0  = (_Float16*)(ws + WS_HB0);
    _Float16* hb1  = (_Float16*)(ws + WS_HB1);
    float*    cst  = (float*)(ws + WS_C);

    k_convX<<<2048, 256, 0, stream>>>(X, Xh);
    k_pack<<<(KTOT * 2048 + 255) / 256, 256, 0, stream>>>(Wih, Whh, Wp);
    k_misc<<<512, 256, 0, stream>>>(bih, bhh, bsum, h0, hb0, c0, cst);

    for (int t = 0; t < T_STEPS; ++t) {
        const _Float16* hp = (t & 1) ? hb1 : hb0;
        _Float16*       hn = (t & 1) ? hb0 : hb1;
        k_step<<<128, 256, 0, stream>>>(Xh, Wp, bsum, hp, hn, cst,
                                        W1, b1, W2, b2, out, t);
    }
    k_ytail<<<8, 256, 0, stream>>>(hb0, W1, b1, W2, b2, out);
}